// Round 4
// baseline (161.078 us; speedup 1.0000x reference)
//
#include <hip/hip_runtime.h>

#define NCELL 24576      // 128*192 feature cells
#define NTOT  221184     // NCELL * 9
#define NBIN13 8192      // 13-bit score-key histogram bins (LDS)
#define TOPN  6000
#define POSTN 300
#define NPADR 6016       // padded candidate count (94 words of 64)
#define NW    94         // suppression-mask words per row
#define CW    8          // words per scan chunk (512 ranks)
#define NCHUNK 12        // ceil(94/8)
#define NCB   16         // compaction blocks
#define SLOT  1024       // cbuf slot per compaction block
#define CAP2  (NCB*SLOT) // 16384 total cbuf slots

// ---------------- decode anchors + scores, build sort keys ----------------
__global__ void decode_kernel(const float* __restrict__ scores,
                              const float* __restrict__ deltas,
                              const float* __restrict__ iminfo,
                              float4* __restrict__ boxes,
                              unsigned* __restrict__ skeys,
                              unsigned short* __restrict__ skeys16) {
#pragma clang fp contract(off)
    int c = blockIdx.x * blockDim.x + threadIdx.x;
    if (c >= NCELL) return;
    const float AW[9] = {184.f,368.f,736.f,128.f,256.f,512.f, 88.f,176.f,352.f};
    const float AH[9] = { 96.f,192.f,384.f,128.f,256.f,512.f,176.f,352.f,704.f};
    float sx = (float)((c >> 7) << 4);   // (c/128)*16  -- 'ij' meshgrid quirk
    float sy = (float)((c & 127) << 4);  // (c%128)*16
    float imh = iminfo[0], imw = iminfo[1], ims = iminfo[2];
    float xhi = imw - 1.0f, yhi = imh - 1.0f;
    float ms = 16.0f * ims;
    float ctrx = sx + 8.0f, ctry = sy + 8.0f;
    const float* sbase = scores + 9 * NCELL + c;
    const float* dbase = deltas + c;
#pragma unroll
    for (int a = 0; a < 9; ++a) {
        float sc = sbase[a * NCELL];
        float dx = dbase[(4 * a + 0) * NCELL];
        float dy = dbase[(4 * a + 1) * NCELL];
        float dw = dbase[(4 * a + 2) * NCELL];
        float dh = dbase[(4 * a + 3) * NCELL];
        float pcx = dx * AW[a] + ctrx;
        float pcy = dy * AH[a] + ctry;
        float pw = expf(dw) * AW[a];
        float ph = expf(dh) * AH[a];
        float x1 = pcx - 0.5f * pw;
        float y1 = pcy - 0.5f * ph;
        float x2 = pcx + 0.5f * pw;
        float y2 = pcy + 0.5f * ph;
        x1 = fminf(fmaxf(x1, 0.0f), xhi);
        x2 = fminf(fmaxf(x2, 0.0f), xhi);
        y1 = fminf(fmaxf(y1, 0.0f), yhi);
        y2 = fminf(fmaxf(y2, 0.0f), yhi);
        bool valid = ((x2 - x1 + 1.0f) >= ms) && ((y2 - y1 + 1.0f) >= ms);
        unsigned u = __float_as_uint(sc);
        unsigned key = (u & 0x80000000u) ? ~u : (u | 0x80000000u);
        if (!valid) key = 0x007FFFFFu;   // sort key of -inf
        boxes[a * NCELL + c] = make_float4(x1, y1, x2, y2);
        skeys[a * NCELL + c] = key;
        skeys16[a * NCELL + c] = (unsigned short)(key >> 16);
    }
}

// ---------------- per-block LDS hist + redundant T + slice compact (16 blocks) ----------------
__global__ __launch_bounds__(1024) void compactT_kernel(const unsigned* __restrict__ skeys,
                                                        const unsigned short* __restrict__ skeys16,
                                                        unsigned* __restrict__ meta16,
                                                        unsigned long long* __restrict__ cbuf) {
    __shared__ unsigned hist[NBIN13];      // 32 KB
    __shared__ unsigned psum[1024];
    __shared__ unsigned csum[256];
    __shared__ unsigned sB, sAbove, sT, sCount;
    int tid = threadIdx.x, bid = blockIdx.x;
    for (int b = tid; b < NBIN13; b += 1024) hist[b] = 0u;
    if (tid == 0) sCount = 0u;
    __syncthreads();
    // full-stream histogram over the 16-bit hi-key stream (every block sees all keys)
    const uint4* s16 = (const uint4*)skeys16;
    for (int q = tid; q < NTOT / 8; q += 1024) {
        uint4 u = s16[q];
        atomicAdd(&hist[(u.x & 0xFFFFu) >> 3], 1u);
        atomicAdd(&hist[u.x >> 19], 1u);
        atomicAdd(&hist[(u.y & 0xFFFFu) >> 3], 1u);
        atomicAdd(&hist[u.y >> 19], 1u);
        atomicAdd(&hist[(u.z & 0xFFFFu) >> 3], 1u);
        atomicAdd(&hist[u.z >> 19], 1u);
        atomicAdd(&hist[(u.w & 0xFFFFu) >> 3], 1u);
        atomicAdd(&hist[u.w >> 19], 1u);
    }
    __syncthreads();
    // threshold T: cum(>=T) >= 6000, cum(>T) < 6000  (identical in every block)
    unsigned s = 0;
#pragma unroll
    for (int q = 0; q < 8; ++q) s += hist[tid * 8 + q];
    psum[tid] = s;
    __syncthreads();
    if (tid < 256)
        csum[tid] = psum[tid * 4] + psum[tid * 4 + 1] + psum[tid * 4 + 2] + psum[tid * 4 + 3];
    __syncthreads();
    if (tid < 64) {
        int lane = tid;
        unsigned c0 = csum[lane * 4 + 0], c1 = csum[lane * 4 + 1];
        unsigned c2 = csum[lane * 4 + 2], c3 = csum[lane * 4 + 3];
        unsigned ls = c0 + c1 + c2 + c3;
        unsigned v = ls;
#pragma unroll
        for (int o = 1; o < 64; o <<= 1) {
            unsigned t = __shfl_down(v, o, 64);
            if (lane + o < 64) v += t;
        }
        unsigned sufExcl = v - ls;
        unsigned a3 = sufExcl;
        unsigned a2 = a3 + c3;
        unsigned a1 = a2 + c2;
        unsigned a0 = a1 + c1;
        if (a0 < TOPN && a0 + c0 >= TOPN) { sB = lane * 4 + 0; sAbove = a0; }
        if (a1 < TOPN && a1 + c1 >= TOPN) { sB = lane * 4 + 1; sAbove = a1; }
        if (a2 < TOPN && a2 + c2 >= TOPN) { sB = lane * 4 + 2; sAbove = a2; }
        if (a3 < TOPN && a3 + c3 >= TOPN) { sB = lane * 4 + 3; sAbove = a3; }
    }
    __syncthreads();
    if (tid < 32) {
        unsigned B = sB, above = sAbove;
        unsigned h = hist[B * 32 + tid];
        unsigned v = h;
#pragma unroll
        for (int o = 1; o < 32; o <<= 1) {
            unsigned t = __shfl_down(v, o, 64);
            if (tid + o < 32) v += t;
        }
        unsigned sufExcl = v - h;
        unsigned ab = above + sufExcl;
        if (ab < TOPN && ab + h >= TOPN) sT = B * 32 + tid;
    }
    __syncthreads();
    // compact OWN slice into private slot (LDS-local positions, no global atomics)
    unsigned T = sT;
    int base = bid * (NTOT / NCB);                  // 13824-element slice
    const uint4* s4b = (const uint4*)(skeys + base);
    for (int q = tid; q < (NTOT / NCB) / 4; q += 1024) {
        uint4 u = s4b[q];
        unsigned k4[4] = {u.x, u.y, u.z, u.w};
#pragma unroll
        for (int k = 0; k < 4; ++k) {
            if ((k4[k] >> 19) >= T) {
                unsigned lp = atomicAdd(&sCount, 1u);
                if (lp < SLOT) {
                    int m = base + 4 * q + k;
                    unsigned n = (unsigned)((m % NCELL) * 9 + (m / NCELL));
                    cbuf[(bid << 10) + lp] =
                        ((unsigned long long)k4[k] << 32) | (unsigned long long)(~n);
                }
            }
        }
    }
    __syncthreads();
    unsigned cnt = sCount; if (cnt > SLOT) cnt = SLOT;
    for (int e = cnt + tid; e < SLOT; e += 1024) cbuf[(bid << 10) + e] = 0ULL;  // pad
    if (tid == 0) meta16[bid] = cnt;
}

// ---------------- rank by counting + scatter over slotted cbuf ----------------
__global__ __launch_bounds__(256) void rankscatter_kernel(const unsigned long long* __restrict__ cbuf,
                                                          const unsigned* __restrict__ meta16,
                                                          const float4* __restrict__ boxes,
                                                          float4* __restrict__ sortedbox) {
    __shared__ unsigned long long jk[512];
    __shared__ unsigned scnt[NCB];
    int tid = threadIdx.x;
    if (tid < NCB) scnt[tid] = meta16[tid];
    __syncthreads();
    int i = blockIdx.x * 32 + (tid >> 3);
    int slice = tid & 7;
    unsigned long long ki = cbuf[i];
    unsigned cr = 0;
    for (int jt = 0; jt < CAP2 / 512; ++jt) {
        int b = jt >> 1;
        unsigned cb = scnt[b];
        if ((jt & 1) ? (cb <= 512u) : (cb == 0u)) continue;   // block-uniform skip
        __syncthreads();
        for (int q = tid; q < 512; q += 256) jk[q] = cbuf[(jt << 9) + q];
        __syncthreads();
#pragma unroll 8
        for (int j = 0; j < 64; ++j) cr += (jk[slice + (j << 3)] > ki) ? 1u : 0u;
    }
    cr += __shfl_down(cr, 4, 8);
    cr += __shfl_down(cr, 2, 8);
    cr += __shfl_down(cr, 1, 8);
    if (slice == 0 && ki != 0ULL && cr < NPADR) {
        unsigned n = ~(unsigned)ki;
        unsigned m = (n % 9u) * (unsigned)NCELL + (n / 9u);
        sortedbox[cr] = boxes[m];
    }
}

// ---------------- all-pairs suppression matrix: word-per-thread ----------------
// grid (24, 94): blockIdx.y = 64-row i-tile; blockIdx.x = one 256-col j-tile.
// rowr is only ever read for words strictly above each row's own diagonal word
// (sdg-staging/B2 in scan read w >= row_chunk_base+CW), so sub-diagonal stores are skipped.
__global__ __launch_bounds__(256) void matrix_kernel(const float4* __restrict__ sortedbox,
                                                     unsigned long long* __restrict__ rowr,
                                                     unsigned long long* __restrict__ diagw,
                                                     unsigned long long* __restrict__ diagT) {
#pragma clang fp contract(off)
    __shared__ float4 jb[256];
    __shared__ float  ja[256];
    int tid = threadIdx.x;
    int lane = tid & 63, wave = tid >> 6;
    int i0 = blockIdx.y << 6;
    int i = i0 + lane;
    int w = (blockIdx.x << 2) + wave;
    int jbase = blockIdx.x << 8;
    unsigned long long word = 0ULL;

    if (jbase + 255 > i0) {                  // tile not entirely below diagonal
        int jg = jbase + tid;
        float4 v = (jg < NPADR) ? sortedbox[jg] : make_float4(0.f, 0.f, 0.f, 0.f);
        jb[tid] = v;
        ja[tid] = (v.z - v.x) * (v.w - v.y);
        __syncthreads();
        if (w < NW && ((w << 6) + 63) > i) { // this word has bits above the diagonal
            float4 bi = sortedbox[i];
            float ai = (bi.z - bi.x) * (bi.w - bi.y);
            int jl0 = wave << 6;
            int jg0 = (w << 6);
#pragma unroll 8
            for (int j = 0; j < 64; ++j) {
                float4 bj = jb[jl0 + j];
                float aj = ja[jl0 + j];
                float iw = fminf(bi.z, bj.z) - fmaxf(bi.x, bj.x);
                float ih = fminf(bi.w, bj.w) - fmaxf(bi.y, bj.y);
                iw = fmaxf(iw, 0.0f);
                ih = fmaxf(ih, 0.0f);
                float inter = iw * ih;
                float denom = fmaxf(ai + aj - inter, 1e-9f);
                bool sup = (jg0 + j > i) && (inter / denom > 0.7f);
                word |= (unsigned long long)sup << j;
            }
        }
    }
    if (w < NW) {
        if (w >= (i >> 6))                   // above/diag words only (sub-diag never read)
            rowr[(size_t)i * NW + w] = word;
        if ((i >> 9) == (w >> 3))            // chunk-diagonal word -> word-major copy
            diagw[((size_t)w << 9) + (i & 511)] = word;
        if (w == (i >> 6)) {                 // exact diag 64x64 block: emit transpose
            unsigned long long col = 0ULL;
#pragma unroll
            for (int jbit = 0; jbit < 64; ++jbit) {
                unsigned long long m = __ballot((word >> jbit) & 1ULL);
                if (lane == jbit) col = m;
            }
            diagT[((size_t)w << 6) + lane] = col;
        }
    }
}

// ---------------- greedy scan: register-resident resolve ∥ stage ∥ B2, 1 barrier/chunk ----------
// 512 threads. Per chunk c (single barrier at end):
//   wave0 : apply kept(c-1) from staged superdiag (sdg, LDS) to register copy of chunk-c words
//           (group-replicated g_own: lanes 8t..8t+7 hold word wbase+t), then fixed-point resolve
//           with 64-lane-parallel in-chunk propagate (8 lanes per target word + shfl_xor reduce).
//           gm[chunk c] is read once, never written back (dead after A(c)).
//   waves1-3: stage chunk c+1: diag block (cblk), diag transpose (ldsT), and superdiagonal
//           block sdg = rows-of-chunk-c x words-of-chunk-c+1 (feeds next chunk's apply).
//   waves4-7: B2: kept(c-1) rows -> gm[words >= wbase+CW] from global rowr.
// Coverage: kept(c-1)->chunk c via sdg@A(c); kept(c-1)->chunks>=c+1 via B2@A(c); older kept
// covered by earlier B2s. Races: B2 writes words >= c+1, resolve touches only chunk-c words
// (registers); keptArr reads [kA,kB) disjoint from resolve writes [kB,...); staged buffers
// double-buffered. Single barrier per chunk suffices.
__global__ __launch_bounds__(512) void scan_kernel(const unsigned long long* __restrict__ rowr,
                                                   const unsigned long long* __restrict__ diagw,
                                                   const unsigned long long* __restrict__ diagT,
                                                   const float4* __restrict__ sortedbox,
                                                   float* __restrict__ out) {
    __shared__ __align__(16) unsigned long long cblk[2][CW * 512]; // 64 KB diag block, word-major
    __shared__ __align__(16) unsigned long long sdg[2][512 * 8];   // 64 KB superdiag, row-major
    __shared__ unsigned long long ldsT[2][CW * 64];                // 8 KB diagT dbuf
    __shared__ unsigned long long gm[128];
    __shared__ int keptArr[POSTN];
    __shared__ int s_kept, s_done;
    int tid = threadIdx.x;
    int lane = tid & 63, wave = tid >> 6;

    if (tid < 128) gm[tid] = (tid == 93) ? ~((1ULL << 48) - 1) : 0ULL; // ranks>=6000 dead
    if (tid == 0) { s_kept = 0; s_done = 0; }
    for (int e = tid; e < CW * 512; e += 512) cblk[0][e] = diagw[e];   // stage chunk 0
    for (int e = tid; e < CW * 64; e += 512) ldsT[0][e] = diagT[e];
    __syncthreads();

    int kA = 0;  // kept count before chunk c-1's resolve
    int kB = 0;  // kept count before chunk c's resolve
    for (int c = 0; c < NCHUNK; ++c) {
        int buf = c & 1, nbuf = buf ^ 1;
        int wbase = c * CW;
        if (wave == 0) {
            // ---- resolve chunk c, fully in registers ----
            int grp = lane >> 3, sub = lane & 7;
            int myw = wbase + grp;
            unsigned long long g_own = (myw < NW) ? gm[myw] : ~0ULL;
            // apply kept(c-1) via staged superdiag (replaces old B1 phase + barrier)
            {
                unsigned long long acc = 0ULL;
                for (int s = kA + sub; s < kB; s += 8)
                    acc |= sdg[buf][((keptArr[s] & 511) << 3) + grp];
                acc |= __shfl_xor(acc, 1, 64);
                acc |= __shfl_xor(acc, 2, 64);
                acc |= __shfl_xor(acc, 4, 64);
                g_own |= acc;
            }
            unsigned long long dgT[CW];
#pragma unroll
            for (int q = 0; q < CW; ++q) dgT[q] = ldsT[buf][(q << 6) + lane];
            unsigned long long lowmask = (1ULL << lane) - 1ULL;
            int kept = kB;
            int done = 0;
            for (int q = 0; q < CW && wbase + q < NW; ++q) {
                unsigned long long lv = __shfl(g_own, q << 3, 64);  // word q (uniform)
                unsigned long long live = ~lv;
                if (wbase + q == NW - 1) live &= (1ULL << 48) - 1;
                if (!live) continue;
                bool alive = (live >> lane) & 1ULL;
                unsigned long long x = live;
                for (;;) {
                    bool sup = (dgT[q] & x & lowmask) != 0ULL;
                    unsigned long long xn = __ballot(alive && !sup);
                    if (xn == x) break;
                    x = xn;
                }
                unsigned long long kb = x;
                if (kb) {
                    int nk = __popcll(kb);
                    int myr = __popcll(kb & lowmask);
                    if (((kb >> lane) & 1ULL) && (kept + myr < POSTN))
                        keptArr[kept + myr] = ((wbase + q) << 6) + lane;
                    kept += nk;
                    if (kept >= POSTN) { kept = POSTN; done = 1; }
                }
                if (kb && !done && q < CW - 1) {
                    // 64-lane in-chunk propagate: 8 lanes per target word, 8 bits each
                    unsigned long long acc = 0ULL;
                    if (grp > q) {
                        int base = (grp << 9) + (q << 6) + sub;
#pragma unroll
                        for (int k = 0; k < 8; ++k)
                            if ((kb >> (sub + (k << 3))) & 1ULL)
                                acc |= cblk[buf][base + (k << 3)];
                    }
                    acc |= __shfl_xor(acc, 1, 64);
                    acc |= __shfl_xor(acc, 2, 64);
                    acc |= __shfl_xor(acc, 4, 64);
                    if (grp > q) g_own |= acc;
                }
                if (done) break;
            }
            if (lane == 0) { s_kept = kept; s_done = done; }
        } else if (wave < 4) {
            // ---- waves 1-3: stage chunk c+1 (cblk + ldsT + superdiag) ----
            if (c + 1 < NCHUNK) {
                int t = tid - 64;                      // 0..191
                int wb2 = wbase + CW;
                int rb2 = wb2 << 6;
                for (int e = t; e < CW * 512; e += 192) {
                    int q = e >> 9, r = e & 511;
                    cblk[nbuf][e] = (wb2 + q < NW && rb2 + r < NPADR)
                        ? diagw[((size_t)(wb2 + q) << 9) + r] : 0ULL;
                }
                for (int e = t; e < CW * 64; e += 192) {
                    int q = e >> 6;
                    ldsT[nbuf][e] = (wb2 + q < NW) ? diagT[((size_t)wb2 << 6) + e] : 0ULL;
                }
                int rowbase = c << 9;                  // rows of chunk c x words of chunk c+1
                for (int e = t; e < 512 * 8; e += 192) {
                    int r = e >> 3, q = e & 7;
                    sdg[nbuf][e] = (wb2 + q < NW)
                        ? rowr[(size_t)(rowbase + r) * NW + wb2 + q] : 0ULL;
                }
            }
        } else {
            // ---- waves 4-7: B2: kept(c-1) rows into gm[words >= wbase+CW] ----
            int nw2 = NW - (wbase + CW);
            int nr2 = kB - kA;
            if (c > 0 && nr2 > 0 && nw2 > 0) {
                int t = tid - 256;                     // 0..255
                int tot = nr2 * nw2;
                for (int idx = t; idx < tot; idx += 256) {
                    int s = idx / nw2, wo = idx - s * nw2;
                    int row = keptArr[kA + s];
                    unsigned long long v = rowr[(size_t)row * NW + (wbase + CW) + wo];
                    if (v) atomicOr(&gm[wbase + CW + wo], v);
                }
            }
        }
        __syncthreads();
        kA = kB;
        kB = s_kept;
        if (s_done != 0 || c == NCHUNK - 1) break;
    }
    __syncthreads();

    int kept = s_kept;
    for (int k = tid; k < POSTN; k += 512) {
        float4 bb = make_float4(0.f, 0.f, 0.f, 0.f);
        if (k < kept) bb = sortedbox[keptArr[k]];
        out[k * 5 + 0] = 0.0f;
        out[k * 5 + 1] = bb.x;
        out[k * 5 + 2] = bb.y;
        out[k * 5 + 3] = bb.z;
        out[k * 5 + 4] = bb.w;
    }
}

extern "C" void kernel_launch(void* const* d_in, const int* in_sizes, int n_in,
                              void* d_out, int out_size, void* d_ws, size_t ws_size,
                              hipStream_t stream) {
    const float* scores = (const float*)d_in[0];
    const float* deltas = (const float*)d_in[1];
    const float* iminfo = (const float*)d_in[2];
    char* w = (char*)d_ws;
    // workspace (~5.9 MB). rowr ALIASES boxes+skeys (both dead after rankscatter).
    float4*   boxes = (float4*)w;                                   // [0, 3538944)
    unsigned* skeys = (unsigned*)(w + 3538944);                     // [3538944, 4423680)
    unsigned long long* rowr = (unsigned long long*)w;              // [0, 4524032) alias
    unsigned* meta16 = (unsigned*)(w + 4786176);                    // 16 words
    unsigned long long* cbuf = (unsigned long long*)(w + 4786240);  // [4786240, 4917312)
    float4* sortedbox = (float4*)(w + 4917312);                     // [4917312, 5013568)
    unsigned long long* diagw = (unsigned long long*)(w + 5013568); // [5013568, 5398592)
    unsigned long long* diagT = (unsigned long long*)(w + 5398592); // [5398592, 5446720)
    unsigned short* skeys16 = (unsigned short*)(w + 5446720);       // [5446720, 5889088)
    float* out = (float*)d_out;

    decode_kernel<<<NCELL / 256, 256, 0, stream>>>(scores, deltas, iminfo, boxes, skeys, skeys16);
    compactT_kernel<<<NCB, 1024, 0, stream>>>(skeys, skeys16, meta16, cbuf);
    rankscatter_kernel<<<CAP2 / 32, 256, 0, stream>>>(cbuf, meta16, boxes, sortedbox);
    matrix_kernel<<<dim3(24, 94), 256, 0, stream>>>(sortedbox, rowr, diagw, diagT);
    scan_kernel<<<1, 512, 0, stream>>>(rowr, diagw, diagT, sortedbox, out);
}

// Round 5
// 157.058 us; speedup vs baseline: 1.0256x; 1.0256x over previous
//
#include <hip/hip_runtime.h>

#define NCELL 24576      // 128*192 feature cells
#define NTOT  221184     // NCELL * 9
#define NBIN13 8192      // 13-bit score-key histogram bins (LDS)
#define TOPN  6000
#define POSTN 300
#define NPADR 6016       // padded candidate count (94 words of 64)
#define NW    94         // suppression-mask words per row
#define CW    8          // words per scan chunk (512 ranks)
#define NCHUNK 12        // ceil(94/8)
#define NCB   16         // compaction blocks
#define SLOT  1024       // cbuf slot per compaction block
#define CAP2  (NCB*SLOT) // 16384 total cbuf slots

// ---------------- decode anchors + scores, build sort keys ----------------
__global__ void decode_kernel(const float* __restrict__ scores,
                              const float* __restrict__ deltas,
                              const float* __restrict__ iminfo,
                              float4* __restrict__ boxes,
                              unsigned* __restrict__ skeys,
                              unsigned short* __restrict__ skeys16) {
#pragma clang fp contract(off)
    int c = blockIdx.x * blockDim.x + threadIdx.x;
    if (c >= NCELL) return;
    const float AW[9] = {184.f,368.f,736.f,128.f,256.f,512.f, 88.f,176.f,352.f};
    const float AH[9] = { 96.f,192.f,384.f,128.f,256.f,512.f,176.f,352.f,704.f};
    float sx = (float)((c >> 7) << 4);   // (c/128)*16  -- 'ij' meshgrid quirk
    float sy = (float)((c & 127) << 4);  // (c%128)*16
    float imh = iminfo[0], imw = iminfo[1], ims = iminfo[2];
    float xhi = imw - 1.0f, yhi = imh - 1.0f;
    float ms = 16.0f * ims;
    float ctrx = sx + 8.0f, ctry = sy + 8.0f;
    const float* sbase = scores + 9 * NCELL + c;
    const float* dbase = deltas + c;
#pragma unroll
    for (int a = 0; a < 9; ++a) {
        float sc = sbase[a * NCELL];
        float dx = dbase[(4 * a + 0) * NCELL];
        float dy = dbase[(4 * a + 1) * NCELL];
        float dw = dbase[(4 * a + 2) * NCELL];
        float dh = dbase[(4 * a + 3) * NCELL];
        float pcx = dx * AW[a] + ctrx;
        float pcy = dy * AH[a] + ctry;
        float pw = expf(dw) * AW[a];
        float ph = expf(dh) * AH[a];
        float x1 = pcx - 0.5f * pw;
        float y1 = pcy - 0.5f * ph;
        float x2 = pcx + 0.5f * pw;
        float y2 = pcy + 0.5f * ph;
        x1 = fminf(fmaxf(x1, 0.0f), xhi);
        x2 = fminf(fmaxf(x2, 0.0f), xhi);
        y1 = fminf(fmaxf(y1, 0.0f), yhi);
        y2 = fminf(fmaxf(y2, 0.0f), yhi);
        bool valid = ((x2 - x1 + 1.0f) >= ms) && ((y2 - y1 + 1.0f) >= ms);
        unsigned u = __float_as_uint(sc);
        unsigned key = (u & 0x80000000u) ? ~u : (u | 0x80000000u);
        if (!valid) key = 0x007FFFFFu;   // sort key of -inf
        boxes[a * NCELL + c] = make_float4(x1, y1, x2, y2);
        skeys[a * NCELL + c] = key;
        skeys16[a * NCELL + c] = (unsigned short)(key >> 16);
    }
}

// ---------------- per-block LDS hist + redundant T + slice compact (16 blocks) ----------------
__global__ __launch_bounds__(1024) void compactT_kernel(const unsigned* __restrict__ skeys,
                                                        const unsigned short* __restrict__ skeys16,
                                                        unsigned* __restrict__ meta16,
                                                        unsigned long long* __restrict__ cbuf) {
    __shared__ unsigned hist[NBIN13];      // 32 KB
    __shared__ unsigned psum[1024];
    __shared__ unsigned csum[256];
    __shared__ unsigned sB, sAbove, sT, sCount;
    int tid = threadIdx.x, bid = blockIdx.x;
    for (int b = tid; b < NBIN13; b += 1024) hist[b] = 0u;
    if (tid == 0) sCount = 0u;
    __syncthreads();
    // full-stream histogram over the 16-bit hi-key stream (every block sees all keys)
    const uint4* s16 = (const uint4*)skeys16;
    for (int q = tid; q < NTOT / 8; q += 1024) {
        uint4 u = s16[q];
        atomicAdd(&hist[(u.x & 0xFFFFu) >> 3], 1u);
        atomicAdd(&hist[u.x >> 19], 1u);
        atomicAdd(&hist[(u.y & 0xFFFFu) >> 3], 1u);
        atomicAdd(&hist[u.y >> 19], 1u);
        atomicAdd(&hist[(u.z & 0xFFFFu) >> 3], 1u);
        atomicAdd(&hist[u.z >> 19], 1u);
        atomicAdd(&hist[(u.w & 0xFFFFu) >> 3], 1u);
        atomicAdd(&hist[u.w >> 19], 1u);
    }
    __syncthreads();
    // threshold T: cum(>=T) >= 6000, cum(>T) < 6000  (identical in every block)
    unsigned s = 0;
#pragma unroll
    for (int q = 0; q < 8; ++q) s += hist[tid * 8 + q];
    psum[tid] = s;
    __syncthreads();
    if (tid < 256)
        csum[tid] = psum[tid * 4] + psum[tid * 4 + 1] + psum[tid * 4 + 2] + psum[tid * 4 + 3];
    __syncthreads();
    if (tid < 64) {
        int lane = tid;
        unsigned c0 = csum[lane * 4 + 0], c1 = csum[lane * 4 + 1];
        unsigned c2 = csum[lane * 4 + 2], c3 = csum[lane * 4 + 3];
        unsigned ls = c0 + c1 + c2 + c3;
        unsigned v = ls;
#pragma unroll
        for (int o = 1; o < 64; o <<= 1) {
            unsigned t = __shfl_down(v, o, 64);
            if (lane + o < 64) v += t;
        }
        unsigned sufExcl = v - ls;
        unsigned a3 = sufExcl;
        unsigned a2 = a3 + c3;
        unsigned a1 = a2 + c2;
        unsigned a0 = a1 + c1;
        if (a0 < TOPN && a0 + c0 >= TOPN) { sB = lane * 4 + 0; sAbove = a0; }
        if (a1 < TOPN && a1 + c1 >= TOPN) { sB = lane * 4 + 1; sAbove = a1; }
        if (a2 < TOPN && a2 + c2 >= TOPN) { sB = lane * 4 + 2; sAbove = a2; }
        if (a3 < TOPN && a3 + c3 >= TOPN) { sB = lane * 4 + 3; sAbove = a3; }
    }
    __syncthreads();
    if (tid < 32) {
        unsigned B = sB, above = sAbove;
        unsigned h = hist[B * 32 + tid];
        unsigned v = h;
#pragma unroll
        for (int o = 1; o < 32; o <<= 1) {
            unsigned t = __shfl_down(v, o, 64);
            if (tid + o < 32) v += t;
        }
        unsigned sufExcl = v - h;
        unsigned ab = above + sufExcl;
        if (ab < TOPN && ab + h >= TOPN) sT = B * 32 + tid;
    }
    __syncthreads();
    // compact OWN slice into private slot (LDS-local positions, no global atomics)
    unsigned T = sT;
    int base = bid * (NTOT / NCB);                  // 13824-element slice
    const uint4* s4b = (const uint4*)(skeys + base);
    for (int q = tid; q < (NTOT / NCB) / 4; q += 1024) {
        uint4 u = s4b[q];
        unsigned k4[4] = {u.x, u.y, u.z, u.w};
#pragma unroll
        for (int k = 0; k < 4; ++k) {
            if ((k4[k] >> 19) >= T) {
                unsigned lp = atomicAdd(&sCount, 1u);
                if (lp < SLOT) {
                    int m = base + 4 * q + k;
                    unsigned n = (unsigned)((m % NCELL) * 9 + (m / NCELL));
                    cbuf[(bid << 10) + lp] =
                        ((unsigned long long)k4[k] << 32) | (unsigned long long)(~n);
                }
            }
        }
    }
    __syncthreads();
    unsigned cnt = sCount; if (cnt > SLOT) cnt = SLOT;
    for (int e = cnt + tid; e < SLOT; e += 1024) cbuf[(bid << 10) + e] = 0ULL;  // pad
    if (tid == 0) meta16[bid] = cnt;
}

// ---------------- rank by counting + scatter over slotted cbuf ----------------
__global__ __launch_bounds__(256) void rankscatter_kernel(const unsigned long long* __restrict__ cbuf,
                                                          const unsigned* __restrict__ meta16,
                                                          const float4* __restrict__ boxes,
                                                          float4* __restrict__ sortedbox) {
    __shared__ unsigned long long jk[512];
    __shared__ unsigned scnt[NCB];
    int tid = threadIdx.x;
    if (tid < NCB) scnt[tid] = meta16[tid];
    __syncthreads();
    int i = blockIdx.x * 32 + (tid >> 3);
    int slice = tid & 7;
    unsigned long long ki = cbuf[i];
    unsigned cr = 0;
    for (int jt = 0; jt < CAP2 / 512; ++jt) {
        int b = jt >> 1;
        unsigned cb = scnt[b];
        if ((jt & 1) ? (cb <= 512u) : (cb == 0u)) continue;   // block-uniform skip
        __syncthreads();
        for (int q = tid; q < 512; q += 256) jk[q] = cbuf[(jt << 9) + q];
        __syncthreads();
#pragma unroll 8
        for (int j = 0; j < 64; ++j) cr += (jk[slice + (j << 3)] > ki) ? 1u : 0u;
    }
    cr += __shfl_down(cr, 4, 8);
    cr += __shfl_down(cr, 2, 8);
    cr += __shfl_down(cr, 1, 8);
    if (slice == 0 && ki != 0ULL && cr < NPADR) {
        unsigned n = ~(unsigned)ki;
        unsigned m = (n % 9u) * (unsigned)NCELL + (n / 9u);
        sortedbox[cr] = boxes[m];
    }
}

// ---------------- all-pairs suppression matrix: word-per-thread ----------------
// grid (24, 94): blockIdx.y = 64-row i-tile; blockIdx.x = one 256-col j-tile.
// rowr is only ever read for words strictly above each row's own diagonal word
// (B1/B2 in scan read w >= row_chunk_base+CW), so sub-diagonal stores are skipped.
__global__ __launch_bounds__(256) void matrix_kernel(const float4* __restrict__ sortedbox,
                                                     unsigned long long* __restrict__ rowr,
                                                     unsigned long long* __restrict__ diagw,
                                                     unsigned long long* __restrict__ diagT) {
#pragma clang fp contract(off)
    __shared__ float4 jb[256];
    __shared__ float  ja[256];
    int tid = threadIdx.x;
    int lane = tid & 63, wave = tid >> 6;
    int i0 = blockIdx.y << 6;
    int i = i0 + lane;
    int w = (blockIdx.x << 2) + wave;
    int jbase = blockIdx.x << 8;
    unsigned long long word = 0ULL;

    if (jbase + 255 > i0) {                  // tile not entirely below diagonal
        int jg = jbase + tid;
        float4 v = (jg < NPADR) ? sortedbox[jg] : make_float4(0.f, 0.f, 0.f, 0.f);
        jb[tid] = v;
        ja[tid] = (v.z - v.x) * (v.w - v.y);
        __syncthreads();
        if (w < NW && ((w << 6) + 63) > i) { // this word has bits above the diagonal
            float4 bi = sortedbox[i];
            float ai = (bi.z - bi.x) * (bi.w - bi.y);
            int jl0 = wave << 6;
            int jg0 = (w << 6);
#pragma unroll 8
            for (int j = 0; j < 64; ++j) {
                float4 bj = jb[jl0 + j];
                float aj = ja[jl0 + j];
                float iw = fminf(bi.z, bj.z) - fmaxf(bi.x, bj.x);
                float ih = fminf(bi.w, bj.w) - fmaxf(bi.y, bj.y);
                iw = fmaxf(iw, 0.0f);
                ih = fmaxf(ih, 0.0f);
                float inter = iw * ih;
                float denom = fmaxf(ai + aj - inter, 1e-9f);
                bool sup = (jg0 + j > i) && (inter / denom > 0.7f);
                word |= (unsigned long long)sup << j;
            }
        }
    }
    if (w < NW) {
        if (w >= (i >> 6))                   // above/diag words only (sub-diag never read)
            rowr[(size_t)i * NW + w] = word;
        if ((i >> 9) == (w >> 3))            // chunk-diagonal word -> word-major copy
            diagw[((size_t)w << 9) + (i & 511)] = word;
        if (w == (i >> 6)) {                 // exact diag 64x64 block: emit transpose
            unsigned long long col = 0ULL;
#pragma unroll
            for (int jbit = 0; jbit < 64; ++jbit) {
                unsigned long long m = __ballot((word >> jbit) & 1ULL);
                if (lane == jbit) col = m;
            }
            diagT[((size_t)w << 6) + lane] = col;
        }
    }
}

// ---------------- greedy scan: fixed-point resolve ∥ lean stage+B2 pool, then tiny B1 ----------
// 512 threads. Per chunk c:
//   wave0  : R3 fixed-point resolve of chunk c (known-good, unchanged).
//   waves1-7 (448-thread pool): (a) stage chunk c+1 -- TRIANGLE-ONLY cblk (target word >
//            source word; the only slots the in-chunk propagate ever reads) + ldsT, all as
//            16B ulonglong2 loads; then (b) B2: kept(c-1) rows -> gm[words >= wbase+CW],
//            16B vectorized. Pool balances early chunks (B2-heavy) vs late (stage-heavy).
//   barrier; B1 (all 512, vectorized pairs): kept(c) -> next-chunk words; barrier.
// Coverage (as R3): kept(c-1)->chunk c via B1(c-1); kept(k<=c-2)->chunk c via B2@A(k+1).
// Races: B2 atomicOrs words >= wbase+CW, resolve touches chunk-c words only; keptArr
// reads [kA,kB) disjoint from resolve writes [kB,...); staged buffers double-buffered.
__global__ __launch_bounds__(512) void scan_kernel(const unsigned long long* __restrict__ rowr,
                                                   const unsigned long long* __restrict__ diagw,
                                                   const unsigned long long* __restrict__ diagT,
                                                   const float4* __restrict__ sortedbox,
                                                   float* __restrict__ out) {
    __shared__ __align__(16) unsigned long long cblk[2][CW * 512]; // 64 KB diag block, word-major
    __shared__ __align__(16) unsigned long long ldsT[2][CW * 64];  // 8 KB diagT dbuf
    __shared__ unsigned long long gm[128];
    __shared__ int keptArr[POSTN];
    __shared__ int s_kept, s_done;
    int tid = threadIdx.x;
    int lane = tid & 63, wave = tid >> 6;

    if (tid < 128) gm[tid] = (tid == 93) ? ~((1ULL << 48) - 1) : 0ULL; // ranks>=6000 dead
    if (tid == 0) { s_kept = 0; s_done = 0; }
    // stage chunk 0: triangle cblk + ldsT, 16B vectorized (all 512 threads)
    for (int pe = tid; pe < CW * 256; pe += 512) {
        int q = pe >> 8, r = (pe & 255) << 1;
        if (q > (r >> 6))
            *(ulonglong2*)&cblk[0][(q << 9) + r] =
                *(const ulonglong2*)&diagw[((size_t)q << 9) + r];
    }
    for (int pe = tid; pe < CW * 32; pe += 512) {
        int e = pe << 1;
        *(ulonglong2*)&ldsT[0][e] = *(const ulonglong2*)&diagT[e];
    }
    __syncthreads();

    int kA = 0;  // kept count before chunk c-1's resolve
    int kB = 0;  // kept count before chunk c's resolve
    for (int c = 0; c < NCHUNK; ++c) {
        int buf = c & 1, nbuf = buf ^ 1;
        int wbase = c * CW;
        if (wave == 0) {
            // ---- resolve chunk c (R3 fixed-point body, unchanged) ----
            unsigned long long dgT[CW];
#pragma unroll
            for (int q = 0; q < CW; ++q) dgT[q] = ldsT[buf][(q << 6) + lane];
            unsigned long long lowmask = (1ULL << lane) - 1ULL;
            int kept = kB;
            int done = 0;
            for (int q = 0; q < CW && wbase + q < NW; ++q) {
                int w = wbase + q;
                unsigned long long live = ~gm[w];
                if (w == NW - 1) live &= (1ULL << 48) - 1;
                if (!live) continue;
                bool alive = (live >> lane) & 1ULL;
                unsigned long long x = live;
                for (;;) {
                    bool sup = (dgT[q] & x & lowmask) != 0ULL;
                    unsigned long long xn = __ballot(alive && !sup);
                    if (xn == x) break;
                    x = xn;
                }
                unsigned long long kb = x;
                if (kb) {
                    int nk = __popcll(kb);
                    int myr = __popcll(kb & lowmask);
                    if (((kb >> lane) & 1ULL) && (kept + myr < POSTN))
                        keptArr[kept + myr] = (w << 6) + lane;
                    kept += nk;
                    if (kept >= POSTN) { kept = POSTN; done = 1; }
                }
                if (kb && !done && q < CW - 1) {
                    // in-chunk MLP propagate to later words of this chunk
                    bool act = (lane > q) && (lane < CW);
                    int base = (lane << 9) + (q << 6);
                    unsigned long long acc = 0ULL;
                    unsigned long long t = kb;
                    while (t) {
                        int b0 = __ffsll((unsigned long long)t) - 1; t &= t - 1;
                        int b1 = 0, b2 = 0, b3 = 0, nb = 1;
                        if (t) { b1 = __ffsll((unsigned long long)t) - 1; t &= t - 1; nb = 2; }
                        if (t) { b2 = __ffsll((unsigned long long)t) - 1; t &= t - 1; nb = 3; }
                        if (t) { b3 = __ffsll((unsigned long long)t) - 1; t &= t - 1; nb = 4; }
                        unsigned long long r0 = act ? cblk[buf][base + b0] : 0ULL;
                        unsigned long long r1 = (act && nb > 1) ? cblk[buf][base + b1] : 0ULL;
                        unsigned long long r2 = (act && nb > 2) ? cblk[buf][base + b2] : 0ULL;
                        unsigned long long r3 = (act && nb > 3) ? cblk[buf][base + b3] : 0ULL;
                        acc |= (r0 | r1) | (r2 | r3);
                    }
                    if (act && acc) atomicOr(&gm[wbase + lane], acc);
                }
                if (done) break;
            }
            if (lane == 0) { s_kept = kept; s_done = done; }
        } else {
            // ---- waves 1-7 pool: stage chunk c+1, then B2 ----
            int t = tid - 64;                          // 0..447
            if (c + 1 < NCHUNK) {
                int wb2 = wbase + CW, rb2 = wb2 << 6;
                for (int pe = t; pe < CW * 256; pe += 448) {
                    int q = pe >> 8, r = (pe & 255) << 1;
                    if (q > (r >> 6)) {                // triangle only (never read otherwise)
                        ulonglong2 v = make_ulonglong2(0ULL, 0ULL);
                        if (wb2 + q < NW && rb2 + r + 1 < NPADR)
                            v = *(const ulonglong2*)&diagw[((size_t)(wb2 + q) << 9) + r];
                        *(ulonglong2*)&cblk[nbuf][(q << 9) + r] = v;
                    }
                }
                for (int pe = t; pe < CW * 32; pe += 448) {
                    int e = pe << 1, q = e >> 6;
                    ulonglong2 v = make_ulonglong2(0ULL, 0ULL);
                    if (wb2 + q < NW) v = *(const ulonglong2*)&diagT[((size_t)wb2 << 6) + e];
                    *(ulonglong2*)&ldsT[nbuf][e] = v;
                }
            }
            {
                // B2: kept(c-1) rows into gm[words >= wbase+CW], 16B vectorized
                int w2 = wbase + CW;
                int nw2 = NW - w2;                     // always even
                int nr2 = kB - kA;
                if (c > 0 && nr2 > 0 && nw2 > 0) {
                    int npair = nw2 >> 1;
                    int tot = nr2 * npair;
                    for (int idx = t; idx < tot; idx += 448) {
                        int s = idx / npair, po = idx - s * npair;
                        int row = keptArr[kA + s];
                        ulonglong2 v = *(const ulonglong2*)&rowr[(size_t)row * NW + w2 + (po << 1)];
                        if (v.x) atomicOr(&gm[w2 + (po << 1)], v.x);
                        if (v.y) atomicOr(&gm[w2 + (po << 1) + 1], v.y);
                    }
                }
            }
        }
        __syncthreads();
        int keptNow = s_kept;
        bool fin = (s_done != 0) || (c == NCHUNK - 1);
        if (!fin && keptNow > kB) {
            // ---- B1 (all 512 threads): kept(c) rows -> next-chunk words, 16B vectorized ----
            int w1 = wbase + CW;
            int nw1 = NW - w1; if (nw1 > CW) nw1 = CW; // always even
            int npair1 = nw1 >> 1;
            int po = tid & 3;
            for (int s = kB + (tid >> 2); s < keptNow; s += 128) {
                if (po < npair1) {
                    int row = keptArr[s];
                    ulonglong2 v = *(const ulonglong2*)&rowr[(size_t)row * NW + w1 + (po << 1)];
                    if (v.x) atomicOr(&gm[w1 + (po << 1)], v.x);
                    if (v.y) atomicOr(&gm[w1 + (po << 1) + 1], v.y);
                }
            }
        }
        kA = kB;
        kB = keptNow;
        if (fin) break;
        __syncthreads();
    }
    __syncthreads();

    int kept = s_kept;
    for (int k = tid; k < POSTN; k += 512) {
        float4 bb = make_float4(0.f, 0.f, 0.f, 0.f);
        if (k < kept) bb = sortedbox[keptArr[k]];
        out[k * 5 + 0] = 0.0f;
        out[k * 5 + 1] = bb.x;
        out[k * 5 + 2] = bb.y;
        out[k * 5 + 3] = bb.z;
        out[k * 5 + 4] = bb.w;
    }
}

extern "C" void kernel_launch(void* const* d_in, const int* in_sizes, int n_in,
                              void* d_out, int out_size, void* d_ws, size_t ws_size,
                              hipStream_t stream) {
    const float* scores = (const float*)d_in[0];
    const float* deltas = (const float*)d_in[1];
    const float* iminfo = (const float*)d_in[2];
    char* w = (char*)d_ws;
    // workspace (~5.9 MB). rowr ALIASES boxes+skeys (both dead after rankscatter).
    float4*   boxes = (float4*)w;                                   // [0, 3538944)
    unsigned* skeys = (unsigned*)(w + 3538944);                     // [3538944, 4423680)
    unsigned long long* rowr = (unsigned long long*)w;              // [0, 4524032) alias
    unsigned* meta16 = (unsigned*)(w + 4786176);                    // 16 words
    unsigned long long* cbuf = (unsigned long long*)(w + 4786240);  // [4786240, 4917312)
    float4* sortedbox = (float4*)(w + 4917312);                     // [4917312, 5013568)
    unsigned long long* diagw = (unsigned long long*)(w + 5013568); // [5013568, 5398592)
    unsigned long long* diagT = (unsigned long long*)(w + 5398592); // [5398592, 5446720)
    unsigned short* skeys16 = (unsigned short*)(w + 5446720);       // [5446720, 5889088)
    float* out = (float*)d_out;

    decode_kernel<<<NCELL / 256, 256, 0, stream>>>(scores, deltas, iminfo, boxes, skeys, skeys16);
    compactT_kernel<<<NCB, 1024, 0, stream>>>(skeys, skeys16, meta16, cbuf);
    rankscatter_kernel<<<CAP2 / 32, 256, 0, stream>>>(cbuf, meta16, boxes, sortedbox);
    matrix_kernel<<<dim3(24, 94), 256, 0, stream>>>(sortedbox, rowr, diagw, diagT);
    scan_kernel<<<1, 512, 0, stream>>>(rowr, diagw, diagT, sortedbox, out);
}

// Round 6
// 148.598 us; speedup vs baseline: 1.0840x; 1.0569x over previous
//
#include <hip/hip_runtime.h>

#define NCELL 24576      // 128*192 feature cells
#define NTOT  221184     // NCELL * 9
#define NBIN13 8192      // 13-bit score-key histogram bins (LDS)
#define TOPN  6000
#define POSTN 300
#define NPADR 6016       // padded candidate count (94 words of 64)
#define NW    94         // suppression-mask words per row
#define CW    8          // words per scan chunk (512 ranks)
#define NCHUNK 12        // ceil(94/8)
#define NCB   16         // compaction blocks
#define SLOT  1024       // cbuf slot per compaction block
#define CAP2  (NCB*SLOT) // 16384 total cbuf slots

// ---------------- decode anchors + scores, build sort keys ----------------
__global__ void decode_kernel(const float* __restrict__ scores,
                              const float* __restrict__ deltas,
                              const float* __restrict__ iminfo,
                              float4* __restrict__ boxes,
                              unsigned* __restrict__ skeys,
                              unsigned short* __restrict__ skeys16) {
#pragma clang fp contract(off)
    int c = blockIdx.x * blockDim.x + threadIdx.x;
    if (c >= NCELL) return;
    const float AW[9] = {184.f,368.f,736.f,128.f,256.f,512.f, 88.f,176.f,352.f};
    const float AH[9] = { 96.f,192.f,384.f,128.f,256.f,512.f,176.f,352.f,704.f};
    float sx = (float)((c >> 7) << 4);   // (c/128)*16  -- 'ij' meshgrid quirk
    float sy = (float)((c & 127) << 4);  // (c%128)*16
    float imh = iminfo[0], imw = iminfo[1], ims = iminfo[2];
    float xhi = imw - 1.0f, yhi = imh - 1.0f;
    float ms = 16.0f * ims;
    float ctrx = sx + 8.0f, ctry = sy + 8.0f;
    const float* sbase = scores + 9 * NCELL + c;
    const float* dbase = deltas + c;
#pragma unroll
    for (int a = 0; a < 9; ++a) {
        float sc = sbase[a * NCELL];
        float dx = dbase[(4 * a + 0) * NCELL];
        float dy = dbase[(4 * a + 1) * NCELL];
        float dw = dbase[(4 * a + 2) * NCELL];
        float dh = dbase[(4 * a + 3) * NCELL];
        float pcx = dx * AW[a] + ctrx;
        float pcy = dy * AH[a] + ctry;
        float pw = expf(dw) * AW[a];
        float ph = expf(dh) * AH[a];
        float x1 = pcx - 0.5f * pw;
        float y1 = pcy - 0.5f * ph;
        float x2 = pcx + 0.5f * pw;
        float y2 = pcy + 0.5f * ph;
        x1 = fminf(fmaxf(x1, 0.0f), xhi);
        x2 = fminf(fmaxf(x2, 0.0f), xhi);
        y1 = fminf(fmaxf(y1, 0.0f), yhi);
        y2 = fminf(fmaxf(y2, 0.0f), yhi);
        bool valid = ((x2 - x1 + 1.0f) >= ms) && ((y2 - y1 + 1.0f) >= ms);
        unsigned u = __float_as_uint(sc);
        unsigned key = (u & 0x80000000u) ? ~u : (u | 0x80000000u);
        if (!valid) key = 0x007FFFFFu;   // sort key of -inf
        boxes[a * NCELL + c] = make_float4(x1, y1, x2, y2);
        skeys[a * NCELL + c] = key;
        skeys16[a * NCELL + c] = (unsigned short)(key >> 16);
    }
}

// ---------------- per-block LDS hist + redundant T + slice compact (16 blocks) ----------------
__global__ __launch_bounds__(1024) void compactT_kernel(const unsigned* __restrict__ skeys,
                                                        const unsigned short* __restrict__ skeys16,
                                                        unsigned* __restrict__ meta16,
                                                        unsigned long long* __restrict__ cbuf) {
    __shared__ unsigned hist[NBIN13];      // 32 KB
    __shared__ unsigned psum[1024];
    __shared__ unsigned csum[256];
    __shared__ unsigned sB, sAbove, sT, sCount;
    int tid = threadIdx.x, bid = blockIdx.x;
    for (int b = tid; b < NBIN13; b += 1024) hist[b] = 0u;
    if (tid == 0) sCount = 0u;
    __syncthreads();
    // full-stream histogram over the 16-bit hi-key stream (every block sees all keys)
    const uint4* s16 = (const uint4*)skeys16;
    for (int q = tid; q < NTOT / 8; q += 1024) {
        uint4 u = s16[q];
        atomicAdd(&hist[(u.x & 0xFFFFu) >> 3], 1u);
        atomicAdd(&hist[u.x >> 19], 1u);
        atomicAdd(&hist[(u.y & 0xFFFFu) >> 3], 1u);
        atomicAdd(&hist[u.y >> 19], 1u);
        atomicAdd(&hist[(u.z & 0xFFFFu) >> 3], 1u);
        atomicAdd(&hist[u.z >> 19], 1u);
        atomicAdd(&hist[(u.w & 0xFFFFu) >> 3], 1u);
        atomicAdd(&hist[u.w >> 19], 1u);
    }
    __syncthreads();
    // threshold T: cum(>=T) >= 6000, cum(>T) < 6000  (identical in every block)
    unsigned s = 0;
#pragma unroll
    for (int q = 0; q < 8; ++q) s += hist[tid * 8 + q];
    psum[tid] = s;
    __syncthreads();
    if (tid < 256)
        csum[tid] = psum[tid * 4] + psum[tid * 4 + 1] + psum[tid * 4 + 2] + psum[tid * 4 + 3];
    __syncthreads();
    if (tid < 64) {
        int lane = tid;
        unsigned c0 = csum[lane * 4 + 0], c1 = csum[lane * 4 + 1];
        unsigned c2 = csum[lane * 4 + 2], c3 = csum[lane * 4 + 3];
        unsigned ls = c0 + c1 + c2 + c3;
        unsigned v = ls;
#pragma unroll
        for (int o = 1; o < 64; o <<= 1) {
            unsigned t = __shfl_down(v, o, 64);
            if (lane + o < 64) v += t;
        }
        unsigned sufExcl = v - ls;
        unsigned a3 = sufExcl;
        unsigned a2 = a3 + c3;
        unsigned a1 = a2 + c2;
        unsigned a0 = a1 + c1;
        if (a0 < TOPN && a0 + c0 >= TOPN) { sB = lane * 4 + 0; sAbove = a0; }
        if (a1 < TOPN && a1 + c1 >= TOPN) { sB = lane * 4 + 1; sAbove = a1; }
        if (a2 < TOPN && a2 + c2 >= TOPN) { sB = lane * 4 + 2; sAbove = a2; }
        if (a3 < TOPN && a3 + c3 >= TOPN) { sB = lane * 4 + 3; sAbove = a3; }
    }
    __syncthreads();
    if (tid < 32) {
        unsigned B = sB, above = sAbove;
        unsigned h = hist[B * 32 + tid];
        unsigned v = h;
#pragma unroll
        for (int o = 1; o < 32; o <<= 1) {
            unsigned t = __shfl_down(v, o, 64);
            if (tid + o < 32) v += t;
        }
        unsigned sufExcl = v - h;
        unsigned ab = above + sufExcl;
        if (ab < TOPN && ab + h >= TOPN) sT = B * 32 + tid;
    }
    __syncthreads();
    // compact OWN slice into private slot (LDS-local positions, no global atomics)
    unsigned T = sT;
    int base = bid * (NTOT / NCB);                  // 13824-element slice
    const uint4* s4b = (const uint4*)(skeys + base);
    for (int q = tid; q < (NTOT / NCB) / 4; q += 1024) {
        uint4 u = s4b[q];
        unsigned k4[4] = {u.x, u.y, u.z, u.w};
#pragma unroll
        for (int k = 0; k < 4; ++k) {
            if ((k4[k] >> 19) >= T) {
                unsigned lp = atomicAdd(&sCount, 1u);
                if (lp < SLOT) {
                    int m = base + 4 * q + k;
                    unsigned n = (unsigned)((m % NCELL) * 9 + (m / NCELL));
                    cbuf[(bid << 10) + lp] =
                        ((unsigned long long)k4[k] << 32) | (unsigned long long)(~n);
                }
            }
        }
    }
    __syncthreads();
    unsigned cnt = sCount; if (cnt > SLOT) cnt = SLOT;
    for (int e = cnt + tid; e < SLOT; e += 1024) cbuf[(bid << 10) + e] = 0ULL;  // pad
    if (tid == 0) meta16[bid] = cnt;
}

// ---------------- rank by counting + scatter over slotted cbuf ----------------
__global__ __launch_bounds__(256) void rankscatter_kernel(const unsigned long long* __restrict__ cbuf,
                                                          const unsigned* __restrict__ meta16,
                                                          const float4* __restrict__ boxes,
                                                          float4* __restrict__ sortedbox) {
    __shared__ unsigned long long jk[512];
    __shared__ unsigned scnt[NCB];
    int tid = threadIdx.x;
    if (tid < NCB) scnt[tid] = meta16[tid];
    __syncthreads();
    int i = blockIdx.x * 32 + (tid >> 3);
    int slice = tid & 7;
    unsigned long long ki = cbuf[i];
    unsigned cr = 0;
    for (int jt = 0; jt < CAP2 / 512; ++jt) {
        int b = jt >> 1;
        unsigned cb = scnt[b];
        if ((jt & 1) ? (cb <= 512u) : (cb == 0u)) continue;   // block-uniform skip
        __syncthreads();
        for (int q = tid; q < 512; q += 256) jk[q] = cbuf[(jt << 9) + q];
        __syncthreads();
#pragma unroll 8
        for (int j = 0; j < 64; ++j) cr += (jk[slice + (j << 3)] > ki) ? 1u : 0u;
    }
    cr += __shfl_down(cr, 4, 8);
    cr += __shfl_down(cr, 2, 8);
    cr += __shfl_down(cr, 1, 8);
    if (slice == 0 && ki != 0ULL && cr < NPADR) {
        unsigned n = ~(unsigned)ki;
        unsigned m = (n % 9u) * (unsigned)NCELL + (n / 9u);
        sortedbox[cr] = boxes[m];
    }
}

// ---------------- all-pairs suppression matrix: word-per-thread ----------------
// grid (24, 94): blockIdx.y = 64-row i-tile; blockIdx.x = one 256-col j-tile.
// rowr: row-major words, only w >= row's diag word (B1/B2 read those).
// diagw now holds TRANSPOSED chunk-triangle 64x64 blocks: slot [(w<<9)+(qs<<6)+j] =
// column j (bits over the 64 rows of source word qs) of block (qs -> w), qs < w within
// the chunk. Consumed by scan's transposed in-chunk propagate. Exact-diag transpose
// still goes to diagT. Sub-diagonal blocks are never stored (never read).
__global__ __launch_bounds__(256) void matrix_kernel(const float4* __restrict__ sortedbox,
                                                     unsigned long long* __restrict__ rowr,
                                                     unsigned long long* __restrict__ diagw,
                                                     unsigned long long* __restrict__ diagT) {
#pragma clang fp contract(off)
    __shared__ float4 jb[256];
    __shared__ float  ja[256];
    int tid = threadIdx.x;
    int lane = tid & 63, wave = tid >> 6;
    int i0 = blockIdx.y << 6;
    int i = i0 + lane;
    int w = (blockIdx.x << 2) + wave;
    int jbase = blockIdx.x << 8;
    unsigned long long word = 0ULL;

    if (jbase + 255 > i0) {                  // tile not entirely below diagonal
        int jg = jbase + tid;
        float4 v = (jg < NPADR) ? sortedbox[jg] : make_float4(0.f, 0.f, 0.f, 0.f);
        jb[tid] = v;
        ja[tid] = (v.z - v.x) * (v.w - v.y);
        __syncthreads();
        if (w < NW && ((w << 6) + 63) > i) { // this word has bits above the diagonal
            float4 bi = sortedbox[i];
            float ai = (bi.z - bi.x) * (bi.w - bi.y);
            int jl0 = wave << 6;
            int jg0 = (w << 6);
#pragma unroll 8
            for (int j = 0; j < 64; ++j) {
                float4 bj = jb[jl0 + j];
                float aj = ja[jl0 + j];
                float iw = fminf(bi.z, bj.z) - fmaxf(bi.x, bj.x);
                float ih = fminf(bi.w, bj.w) - fmaxf(bi.y, bj.y);
                iw = fmaxf(iw, 0.0f);
                ih = fmaxf(ih, 0.0f);
                float inter = iw * ih;
                float denom = fmaxf(ai + aj - inter, 1e-9f);
                bool sup = (jg0 + j > i) && (inter / denom > 0.7f);
                word |= (unsigned long long)sup << j;
            }
        }
    }
    if (w < NW) {
        if (w >= (i >> 6))                   // above/diag words only (sub-diag never read)
            rowr[(size_t)i * NW + w] = word;
        if ((i >> 9) == (w >> 3) && w >= (i >> 6)) {
            // chunk-region block at/above diagonal: transpose via 64 ballots
            unsigned long long col = 0ULL;
#pragma unroll
            for (int jbit = 0; jbit < 64; ++jbit) {
                unsigned long long m = __ballot((word >> jbit) & 1ULL);
                if (lane == jbit) col = m;
            }
            if (w == (i >> 6))
                diagT[((size_t)w << 6) + lane] = col;         // exact diag block
            else
                diagw[((size_t)w << 9) + (i & 511)] = col;    // transposed triangle block
        }
    }
}

// ---------------- greedy scan: transposed-propagate resolve ∥ stage+B2 pool, then B1 ----------
// 512 threads. Per chunk c:
//   wave0  : prefetch gm[wbase..wbase+7] (one LDS round), then per word q: fixed-point
//            resolve (live = ~(gml|ballot(chunk_sup bit q))); propagate to later words via
//            TRANSPOSED blocks: lane j tests cblkT[t][q][j] & kb -- 8 independent LDS reads,
//            one latency round, no bit-extraction, no gm writes (chunk-c gm dead after A(c)).
//   waves1-7 pool: stage chunk c+1 (transposed triangle cblk + ldsT, 16B loads), then B2:
//            kept(c-1) rows -> gm[words >= wbase+CW] from row-major rowr.
//   barrier; B1 (all 512): kept(c) -> next-chunk words; barrier.
// Coverage: kept(c-1)->chunk c via B1(c-1); kept(k<=c-2)->chunk c via B2@A(k+1); in-chunk
// via chunk_sup. Races: helpers atomicOr only words >= wbase+CW (gml prefetch unaffected);
// keptArr reads [kA,kB) disjoint from resolve writes [kB,...); buffers double-buffered.
__global__ __launch_bounds__(512) void scan_kernel(const unsigned long long* __restrict__ rowr,
                                                   const unsigned long long* __restrict__ diagw,
                                                   const unsigned long long* __restrict__ diagT,
                                                   const float4* __restrict__ sortedbox,
                                                   float* __restrict__ out) {
    __shared__ __align__(16) unsigned long long cblk[2][CW * 512]; // 64 KB transposed blocks
    __shared__ __align__(16) unsigned long long ldsT[2][CW * 64];  // 8 KB diagT dbuf
    __shared__ unsigned long long gm[128];
    __shared__ int keptArr[POSTN];
    __shared__ int s_kept, s_done;
    int tid = threadIdx.x;
    int lane = tid & 63, wave = tid >> 6;

    if (tid < 128) gm[tid] = (tid == 93) ? ~((1ULL << 48) - 1) : 0ULL; // ranks>=6000 dead
    if (tid == 0) { s_kept = 0; s_done = 0; }
    // stage chunk 0: triangle cblkT + ldsT, 16B vectorized (all 512 threads)
    for (int pe = tid; pe < CW * 256; pe += 512) {
        int q = pe >> 8, r = (pe & 255) << 1;
        if (q > (r >> 6))
            *(ulonglong2*)&cblk[0][(q << 9) + r] =
                *(const ulonglong2*)&diagw[((size_t)q << 9) + r];
    }
    for (int pe = tid; pe < CW * 32; pe += 512) {
        int e = pe << 1;
        *(ulonglong2*)&ldsT[0][e] = *(const ulonglong2*)&diagT[e];
    }
    __syncthreads();

    int kA = 0;  // kept count before chunk c-1's resolve
    int kB = 0;  // kept count before chunk c's resolve
    for (int c = 0; c < NCHUNK; ++c) {
        int buf = c & 1, nbuf = buf ^ 1;
        int wbase = c * CW;
        if (wave == 0) {
            // ---- resolve chunk c: transposed propagate, register chunk state ----
            unsigned long long dgT[CW];
            unsigned long long gml[CW];
#pragma unroll
            for (int q = 0; q < CW; ++q) dgT[q] = ldsT[buf][(q << 6) + lane];
#pragma unroll
            for (int q = 0; q < CW; ++q) gml[q] = (wbase + q < NW) ? gm[wbase + q] : ~0ULL;
            unsigned long long lowmask = (1ULL << lane) - 1ULL;
            unsigned chunk_sup = 0;      // bit t: this lane suppressed in word t by chunk kept
            int kept = kB;
            int done = 0;
            int qmax = (NW - wbase < CW) ? (NW - wbase) : CW;
            for (int q = 0; q < qmax; ++q) {
                unsigned long long csup = __ballot((chunk_sup >> q) & 1u);
                unsigned long long live = ~(gml[q] | csup);
                if (wbase + q == NW - 1) live &= (1ULL << 48) - 1;
                if (!live) continue;
                bool alive = (live >> lane) & 1ULL;
                unsigned long long x = live;
                for (;;) {
                    bool sup = (dgT[q] & x & lowmask) != 0ULL;
                    unsigned long long xn = __ballot(alive && !sup);
                    if (xn == x) break;
                    x = xn;
                }
                unsigned long long kb = x;
                if (kb) {
                    int nk = __popcll(kb);
                    int myr = __popcll(kb & lowmask);
                    if (((kb >> lane) & 1ULL) && (kept + myr < POSTN))
                        keptArr[kept + myr] = ((wbase + q) << 6) + lane;
                    kept += nk;
                    if (kept >= POSTN) { kept = POSTN; done = 1; break; }
                    if (q < CW - 1) {
                        // one parallel LDS round: lane j tests column j of each later word
                        unsigned long long pr[CW];
#pragma unroll
                        for (int t = 0; t < CW; ++t)
                            pr[t] = cblk[buf][(t << 9) + (q << 6) + lane];
#pragma unroll
                        for (int t = 0; t < CW; ++t)
                            if (t > q && (pr[t] & kb)) chunk_sup |= 1u << t;
                    }
                }
            }
            if (lane == 0) { s_kept = kept; s_done = done; }
        } else {
            // ---- waves 1-7 pool: stage chunk c+1 (transposed), then B2 ----
            int t = tid - 64;                          // 0..447
            if (c + 1 < NCHUNK) {
                int wb2 = wbase + CW;
                for (int pe = t; pe < CW * 256; pe += 448) {
                    int q = pe >> 8, r = (pe & 255) << 1;
                    if (q > (r >> 6)) {                // triangle only (never read otherwise)
                        ulonglong2 v = make_ulonglong2(0ULL, 0ULL);
                        if (wb2 + q < NW && wb2 + (r >> 6) < NW)   // target+source words valid
                            v = *(const ulonglong2*)&diagw[((size_t)(wb2 + q) << 9) + r];
                        *(ulonglong2*)&cblk[nbuf][(q << 9) + r] = v;
                    }
                }
                for (int pe = t; pe < CW * 32; pe += 448) {
                    int e = pe << 1, q = e >> 6;
                    ulonglong2 v = make_ulonglong2(0ULL, 0ULL);
                    if (wb2 + q < NW) v = *(const ulonglong2*)&diagT[((size_t)wb2 << 6) + e];
                    *(ulonglong2*)&ldsT[nbuf][e] = v;
                }
            }
            {
                // B2: kept(c-1) rows into gm[words >= wbase+CW], 16B vectorized
                int w2 = wbase + CW;
                int nw2 = NW - w2;                     // always even
                int nr2 = kB - kA;
                if (c > 0 && nr2 > 0 && nw2 > 0) {
                    int npair = nw2 >> 1;
                    int tot = nr2 * npair;
                    for (int idx = t; idx < tot; idx += 448) {
                        int s = idx / npair, po = idx - s * npair;
                        int row = keptArr[kA + s];
                        ulonglong2 v = *(const ulonglong2*)&rowr[(size_t)row * NW + w2 + (po << 1)];
                        if (v.x) atomicOr(&gm[w2 + (po << 1)], v.x);
                        if (v.y) atomicOr(&gm[w2 + (po << 1) + 1], v.y);
                    }
                }
            }
        }
        __syncthreads();
        int keptNow = s_kept;
        bool fin = (s_done != 0) || (c == NCHUNK - 1);
        if (!fin && keptNow > kB) {
            // ---- B1 (all 512 threads): kept(c) rows -> next-chunk words, 16B vectorized ----
            int w1 = wbase + CW;
            int nw1 = NW - w1; if (nw1 > CW) nw1 = CW; // always even
            int npair1 = nw1 >> 1;
            int po = tid & 3;
            for (int s = kB + (tid >> 2); s < keptNow; s += 128) {
                if (po < npair1) {
                    int row = keptArr[s];
                    ulonglong2 v = *(const ulonglong2*)&rowr[(size_t)row * NW + w1 + (po << 1)];
                    if (v.x) atomicOr(&gm[w1 + (po << 1)], v.x);
                    if (v.y) atomicOr(&gm[w1 + (po << 1) + 1], v.y);
                }
            }
        }
        kA = kB;
        kB = keptNow;
        if (fin) break;
        __syncthreads();
    }
    __syncthreads();

    int kept = s_kept;
    for (int k = tid; k < POSTN; k += 512) {
        float4 bb = make_float4(0.f, 0.f, 0.f, 0.f);
        if (k < kept) bb = sortedbox[keptArr[k]];
        out[k * 5 + 0] = 0.0f;
        out[k * 5 + 1] = bb.x;
        out[k * 5 + 2] = bb.y;
        out[k * 5 + 3] = bb.z;
        out[k * 5 + 4] = bb.w;
    }
}

extern "C" void kernel_launch(void* const* d_in, const int* in_sizes, int n_in,
                              void* d_out, int out_size, void* d_ws, size_t ws_size,
                              hipStream_t stream) {
    const float* scores = (const float*)d_in[0];
    const float* deltas = (const float*)d_in[1];
    const float* iminfo = (const float*)d_in[2];
    char* w = (char*)d_ws;
    // workspace (~5.9 MB). rowr ALIASES boxes+skeys (both dead after rankscatter).
    float4*   boxes = (float4*)w;                                   // [0, 3538944)
    unsigned* skeys = (unsigned*)(w + 3538944);                     // [3538944, 4423680)
    unsigned long long* rowr = (unsigned long long*)w;              // [0, 4524032) alias
    unsigned* meta16 = (unsigned*)(w + 4786176);                    // 16 words
    unsigned long long* cbuf = (unsigned long long*)(w + 4786240);  // [4786240, 4917312)
    float4* sortedbox = (float4*)(w + 4917312);                     // [4917312, 5013568)
    unsigned long long* diagw = (unsigned long long*)(w + 5013568); // [5013568, 5398592)
    unsigned long long* diagT = (unsigned long long*)(w + 5398592); // [5398592, 5446720)
    unsigned short* skeys16 = (unsigned short*)(w + 5446720);       // [5446720, 5889088)
    float* out = (float*)d_out;

    decode_kernel<<<NCELL / 256, 256, 0, stream>>>(scores, deltas, iminfo, boxes, skeys, skeys16);
    compactT_kernel<<<NCB, 1024, 0, stream>>>(skeys, skeys16, meta16, cbuf);
    rankscatter_kernel<<<CAP2 / 32, 256, 0, stream>>>(cbuf, meta16, boxes, sortedbox);
    matrix_kernel<<<dim3(24, 94), 256, 0, stream>>>(sortedbox, rowr, diagw, diagT);
    scan_kernel<<<1, 512, 0, stream>>>(rowr, diagw, diagT, sortedbox, out);
}

// Round 7
// 135.663 us; speedup vs baseline: 1.1873x; 1.0954x over previous
//
#include <hip/hip_runtime.h>

#define NCELL 24576      // 128*192 feature cells
#define NTOT  221184     // NCELL * 9
#define NBIN13 8192      // 13-bit score-key histogram bins (LDS)
#define TOPN  6000
#define POSTN 300
#define NPADR 6016       // padded candidate count (94 words of 64)
#define NW    94         // suppression-mask words per row
#define CW    8          // words per scan chunk (512 ranks)
#define NCHUNK 12        // ceil(94/8)
#define NCB   16         // compaction blocks
#define SLOT  1024       // cbuf slot per compaction block
#define CAP2  (NCB*SLOT) // 16384 total cbuf slots

// ---------------- decode anchors + scores, build sort keys + fused global hist ----------------
// ghist must be zeroed (hipMemsetAsync) before this launch. Each block histograms its own
// 2304 keys in LDS, then flushes nonzero bins via device-scope atomicAdd (bin-identical to
// the old per-block full-stream histogram, computed once instead of 16x).
__global__ void decode_kernel(const float* __restrict__ scores,
                              const float* __restrict__ deltas,
                              const float* __restrict__ iminfo,
                              float4* __restrict__ boxes,
                              unsigned* __restrict__ skeys,
                              unsigned* __restrict__ ghist) {
#pragma clang fp contract(off)
    __shared__ unsigned lhist[NBIN13];     // 32 KB
    int tid = threadIdx.x;
    for (int b = tid; b < NBIN13; b += 256) lhist[b] = 0u;
    __syncthreads();
    int c = blockIdx.x * blockDim.x + tid;
    if (c < NCELL) {
        const float AW[9] = {184.f,368.f,736.f,128.f,256.f,512.f, 88.f,176.f,352.f};
        const float AH[9] = { 96.f,192.f,384.f,128.f,256.f,512.f,176.f,352.f,704.f};
        float sx = (float)((c >> 7) << 4);   // (c/128)*16  -- 'ij' meshgrid quirk
        float sy = (float)((c & 127) << 4);  // (c%128)*16
        float imh = iminfo[0], imw = iminfo[1], ims = iminfo[2];
        float xhi = imw - 1.0f, yhi = imh - 1.0f;
        float ms = 16.0f * ims;
        float ctrx = sx + 8.0f, ctry = sy + 8.0f;
        const float* sbase = scores + 9 * NCELL + c;
        const float* dbase = deltas + c;
#pragma unroll
        for (int a = 0; a < 9; ++a) {
            float sc = sbase[a * NCELL];
            float dx = dbase[(4 * a + 0) * NCELL];
            float dy = dbase[(4 * a + 1) * NCELL];
            float dw = dbase[(4 * a + 2) * NCELL];
            float dh = dbase[(4 * a + 3) * NCELL];
            float pcx = dx * AW[a] + ctrx;
            float pcy = dy * AH[a] + ctry;
            float pw = expf(dw) * AW[a];
            float ph = expf(dh) * AH[a];
            float x1 = pcx - 0.5f * pw;
            float y1 = pcy - 0.5f * ph;
            float x2 = pcx + 0.5f * pw;
            float y2 = pcy + 0.5f * ph;
            x1 = fminf(fmaxf(x1, 0.0f), xhi);
            x2 = fminf(fmaxf(x2, 0.0f), xhi);
            y1 = fminf(fmaxf(y1, 0.0f), yhi);
            y2 = fminf(fmaxf(y2, 0.0f), yhi);
            bool valid = ((x2 - x1 + 1.0f) >= ms) && ((y2 - y1 + 1.0f) >= ms);
            unsigned u = __float_as_uint(sc);
            unsigned key = (u & 0x80000000u) ? ~u : (u | 0x80000000u);
            if (!valid) key = 0x007FFFFFu;   // sort key of -inf
            boxes[a * NCELL + c] = make_float4(x1, y1, x2, y2);
            skeys[a * NCELL + c] = key;
            atomicAdd(&lhist[key >> 19], 1u);
        }
    }
    __syncthreads();
    for (int b = tid; b < NBIN13; b += 256) {
        unsigned v = lhist[b];
        if (v) atomicAdd(&ghist[b], v);      // device-scope, cross-XCD safe
    }
}

// ---------------- per-block T-find (from precomputed ghist) + slice compact (16 blocks) -------
__global__ __launch_bounds__(1024) void compactT_kernel(const unsigned* __restrict__ skeys,
                                                        const unsigned* __restrict__ ghist,
                                                        unsigned* __restrict__ meta16,
                                                        unsigned long long* __restrict__ cbuf) {
    __shared__ unsigned hist[NBIN13];      // 32 KB
    __shared__ unsigned psum[1024];
    __shared__ unsigned csum[256];
    __shared__ unsigned sB, sAbove, sT, sCount;
    int tid = threadIdx.x, bid = blockIdx.x;
    // load the finished histogram (2 x uint4 per thread)
    {
        const uint4* gh4 = (const uint4*)ghist;
        uint4* h4 = (uint4*)hist;
        for (int q = tid; q < NBIN13 / 4; q += 1024) h4[q] = gh4[q];
    }
    if (tid == 0) sCount = 0u;
    __syncthreads();
    // threshold T: cum(>=T) >= 6000, cum(>T) < 6000  (identical in every block)
    unsigned s = 0;
#pragma unroll
    for (int q = 0; q < 8; ++q) s += hist[tid * 8 + q];
    psum[tid] = s;
    __syncthreads();
    if (tid < 256)
        csum[tid] = psum[tid * 4] + psum[tid * 4 + 1] + psum[tid * 4 + 2] + psum[tid * 4 + 3];
    __syncthreads();
    if (tid < 64) {
        int lane = tid;
        unsigned c0 = csum[lane * 4 + 0], c1 = csum[lane * 4 + 1];
        unsigned c2 = csum[lane * 4 + 2], c3 = csum[lane * 4 + 3];
        unsigned ls = c0 + c1 + c2 + c3;
        unsigned v = ls;
#pragma unroll
        for (int o = 1; o < 64; o <<= 1) {
            unsigned t = __shfl_down(v, o, 64);
            if (lane + o < 64) v += t;
        }
        unsigned sufExcl = v - ls;
        unsigned a3 = sufExcl;
        unsigned a2 = a3 + c3;
        unsigned a1 = a2 + c2;
        unsigned a0 = a1 + c1;
        if (a0 < TOPN && a0 + c0 >= TOPN) { sB = lane * 4 + 0; sAbove = a0; }
        if (a1 < TOPN && a1 + c1 >= TOPN) { sB = lane * 4 + 1; sAbove = a1; }
        if (a2 < TOPN && a2 + c2 >= TOPN) { sB = lane * 4 + 2; sAbove = a2; }
        if (a3 < TOPN && a3 + c3 >= TOPN) { sB = lane * 4 + 3; sAbove = a3; }
    }
    __syncthreads();
    if (tid < 32) {
        unsigned B = sB, above = sAbove;
        unsigned h = hist[B * 32 + tid];
        unsigned v = h;
#pragma unroll
        for (int o = 1; o < 32; o <<= 1) {
            unsigned t = __shfl_down(v, o, 64);
            if (tid + o < 32) v += t;
        }
        unsigned sufExcl = v - h;
        unsigned ab = above + sufExcl;
        if (ab < TOPN && ab + h >= TOPN) sT = B * 32 + tid;
    }
    __syncthreads();
    // compact OWN slice into private slot (LDS-local positions, no global atomics)
    unsigned T = sT;
    int base = bid * (NTOT / NCB);                  // 13824-element slice
    const uint4* s4b = (const uint4*)(skeys + base);
    for (int q = tid; q < (NTOT / NCB) / 4; q += 1024) {
        uint4 u = s4b[q];
        unsigned k4[4] = {u.x, u.y, u.z, u.w};
#pragma unroll
        for (int k = 0; k < 4; ++k) {
            if ((k4[k] >> 19) >= T) {
                unsigned lp = atomicAdd(&sCount, 1u);
                if (lp < SLOT) {
                    int m = base + 4 * q + k;
                    unsigned n = (unsigned)((m % NCELL) * 9 + (m / NCELL));
                    cbuf[(bid << 10) + lp] =
                        ((unsigned long long)k4[k] << 32) | (unsigned long long)(~n);
                }
            }
        }
    }
    __syncthreads();
    unsigned cnt = sCount; if (cnt > SLOT) cnt = SLOT;
    for (int e = cnt + tid; e < SLOT; e += 1024) cbuf[(bid << 10) + e] = 0ULL;  // pad
    if (tid == 0) meta16[bid] = cnt;
}

// ---------------- rank by counting + scatter over slotted cbuf ----------------
__global__ __launch_bounds__(256) void rankscatter_kernel(const unsigned long long* __restrict__ cbuf,
                                                          const unsigned* __restrict__ meta16,
                                                          const float4* __restrict__ boxes,
                                                          float4* __restrict__ sortedbox) {
    __shared__ unsigned long long jk[512];
    __shared__ unsigned scnt[NCB];
    int tid = threadIdx.x;
    if (tid < NCB) scnt[tid] = meta16[tid];
    __syncthreads();
    int i = blockIdx.x * 32 + (tid >> 3);
    int slice = tid & 7;
    unsigned long long ki = cbuf[i];
    unsigned cr = 0;
    for (int jt = 0; jt < CAP2 / 512; ++jt) {
        int b = jt >> 1;
        unsigned cb = scnt[b];
        if ((jt & 1) ? (cb <= 512u) : (cb == 0u)) continue;   // block-uniform skip
        __syncthreads();
        for (int q = tid; q < 512; q += 256) jk[q] = cbuf[(jt << 9) + q];
        __syncthreads();
#pragma unroll 8
        for (int j = 0; j < 64; ++j) cr += (jk[slice + (j << 3)] > ki) ? 1u : 0u;
    }
    cr += __shfl_down(cr, 4, 8);
    cr += __shfl_down(cr, 2, 8);
    cr += __shfl_down(cr, 1, 8);
    if (slice == 0 && ki != 0ULL && cr < NPADR) {
        unsigned n = ~(unsigned)ki;
        unsigned m = (n % 9u) * (unsigned)NCELL + (n / 9u);
        sortedbox[cr] = boxes[m];
    }
}

// ---------------- all-pairs suppression matrix: word-per-thread ----------------
// grid (24, 94): blockIdx.y = 64-row i-tile; blockIdx.x = one 256-col j-tile.
// rowr: row-major words, only w >= row's diag word (B1/B2 read those).
// diagw holds TRANSPOSED chunk-triangle 64x64 blocks: slot [(w<<9)+(qs<<6)+j] =
// column j (bits over the 64 rows of source word qs) of block (qs -> w), qs < w within
// the chunk. Consumed by scan's transposed in-chunk propagate. Exact-diag transpose
// still goes to diagT. Sub-diagonal blocks are never stored (never read).
__global__ __launch_bounds__(256) void matrix_kernel(const float4* __restrict__ sortedbox,
                                                     unsigned long long* __restrict__ rowr,
                                                     unsigned long long* __restrict__ diagw,
                                                     unsigned long long* __restrict__ diagT) {
#pragma clang fp contract(off)
    __shared__ float4 jb[256];
    __shared__ float  ja[256];
    int tid = threadIdx.x;
    int lane = tid & 63, wave = tid >> 6;
    int i0 = blockIdx.y << 6;
    int i = i0 + lane;
    int w = (blockIdx.x << 2) + wave;
    int jbase = blockIdx.x << 8;
    unsigned long long word = 0ULL;

    if (jbase + 255 > i0) {                  // tile not entirely below diagonal
        int jg = jbase + tid;
        float4 v = (jg < NPADR) ? sortedbox[jg] : make_float4(0.f, 0.f, 0.f, 0.f);
        jb[tid] = v;
        ja[tid] = (v.z - v.x) * (v.w - v.y);
        __syncthreads();
        if (w < NW && ((w << 6) + 63) > i) { // this word has bits above the diagonal
            float4 bi = sortedbox[i];
            float ai = (bi.z - bi.x) * (bi.w - bi.y);
            int jl0 = wave << 6;
            int jg0 = (w << 6);
#pragma unroll 8
            for (int j = 0; j < 64; ++j) {
                float4 bj = jb[jl0 + j];
                float aj = ja[jl0 + j];
                float iw = fminf(bi.z, bj.z) - fmaxf(bi.x, bj.x);
                float ih = fminf(bi.w, bj.w) - fmaxf(bi.y, bj.y);
                iw = fmaxf(iw, 0.0f);
                ih = fmaxf(ih, 0.0f);
                float inter = iw * ih;
                float denom = fmaxf(ai + aj - inter, 1e-9f);
                bool sup = (jg0 + j > i) && (inter / denom > 0.7f);
                word |= (unsigned long long)sup << j;
            }
        }
    }
    if (w < NW) {
        if (w >= (i >> 6))                   // above/diag words only (sub-diag never read)
            rowr[(size_t)i * NW + w] = word;
        if ((i >> 9) == (w >> 3) && w >= (i >> 6)) {
            // chunk-region block at/above diagonal: transpose via 64 ballots
            unsigned long long col = 0ULL;
#pragma unroll
            for (int jbit = 0; jbit < 64; ++jbit) {
                unsigned long long m = __ballot((word >> jbit) & 1ULL);
                if (lane == jbit) col = m;
            }
            if (w == (i >> 6))
                diagT[((size_t)w << 6) + lane] = col;         // exact diag block
            else
                diagw[((size_t)w << 9) + (i & 511)] = col;    // transposed triangle block
        }
    }
}

// ---------------- greedy scan: transposed-propagate resolve ∥ stage+B2 pool, then B1 ----------
// 512 threads. Per chunk c:
//   wave0  : prefetch gm[wbase..wbase+7] (one LDS round), then per word q: fixed-point
//            resolve (live = ~(gml|ballot(chunk_sup bit q))); propagate to later words via
//            TRANSPOSED blocks: lane j tests cblkT[t][q][j] & kb -- 8 independent LDS reads,
//            one latency round, no bit-extraction, no gm writes (chunk-c gm dead after A(c)).
//   waves1-7 pool: stage chunk c+1 (transposed triangle cblk + ldsT, 16B loads), then B2:
//            kept(c-1) rows -> gm[words >= wbase+CW] from row-major rowr.
//   barrier; B1 (all 512): kept(c) -> next-chunk words; barrier.
// Coverage: kept(c-1)->chunk c via B1(c-1); kept(k<=c-2)->chunk c via B2@A(k+1); in-chunk
// via chunk_sup. Races: helpers atomicOr only words >= wbase+CW (gml prefetch unaffected);
// keptArr reads [kA,kB) disjoint from resolve writes [kB,...); buffers double-buffered.
__global__ __launch_bounds__(512) void scan_kernel(const unsigned long long* __restrict__ rowr,
                                                   const unsigned long long* __restrict__ diagw,
                                                   const unsigned long long* __restrict__ diagT,
                                                   const float4* __restrict__ sortedbox,
                                                   float* __restrict__ out) {
    __shared__ __align__(16) unsigned long long cblk[2][CW * 512]; // 64 KB transposed blocks
    __shared__ __align__(16) unsigned long long ldsT[2][CW * 64];  // 8 KB diagT dbuf
    __shared__ unsigned long long gm[128];
    __shared__ int keptArr[POSTN];
    __shared__ int s_kept, s_done;
    int tid = threadIdx.x;
    int lane = tid & 63, wave = tid >> 6;

    if (tid < 128) gm[tid] = (tid == 93) ? ~((1ULL << 48) - 1) : 0ULL; // ranks>=6000 dead
    if (tid == 0) { s_kept = 0; s_done = 0; }
    // stage chunk 0: triangle cblkT + ldsT, 16B vectorized (all 512 threads)
    for (int pe = tid; pe < CW * 256; pe += 512) {
        int q = pe >> 8, r = (pe & 255) << 1;
        if (q > (r >> 6))
            *(ulonglong2*)&cblk[0][(q << 9) + r] =
                *(const ulonglong2*)&diagw[((size_t)q << 9) + r];
    }
    for (int pe = tid; pe < CW * 32; pe += 512) {
        int e = pe << 1;
        *(ulonglong2*)&ldsT[0][e] = *(const ulonglong2*)&diagT[e];
    }
    __syncthreads();

    int kA = 0;  // kept count before chunk c-1's resolve
    int kB = 0;  // kept count before chunk c's resolve
    for (int c = 0; c < NCHUNK; ++c) {
        int buf = c & 1, nbuf = buf ^ 1;
        int wbase = c * CW;
        if (wave == 0) {
            // ---- resolve chunk c: transposed propagate, register chunk state ----
            unsigned long long dgT[CW];
            unsigned long long gml[CW];
#pragma unroll
            for (int q = 0; q < CW; ++q) dgT[q] = ldsT[buf][(q << 6) + lane];
#pragma unroll
            for (int q = 0; q < CW; ++q) gml[q] = (wbase + q < NW) ? gm[wbase + q] : ~0ULL;
            unsigned long long lowmask = (1ULL << lane) - 1ULL;
            unsigned chunk_sup = 0;      // bit t: this lane suppressed in word t by chunk kept
            int kept = kB;
            int done = 0;
            int qmax = (NW - wbase < CW) ? (NW - wbase) : CW;
            for (int q = 0; q < qmax; ++q) {
                unsigned long long csup = __ballot((chunk_sup >> q) & 1u);
                unsigned long long live = ~(gml[q] | csup);
                if (wbase + q == NW - 1) live &= (1ULL << 48) - 1;
                if (!live) continue;
                bool alive = (live >> lane) & 1ULL;
                unsigned long long x = live;
                for (;;) {
                    bool sup = (dgT[q] & x & lowmask) != 0ULL;
                    unsigned long long xn = __ballot(alive && !sup);
                    if (xn == x) break;
                    x = xn;
                }
                unsigned long long kb = x;
                if (kb) {
                    int nk = __popcll(kb);
                    int myr = __popcll(kb & lowmask);
                    if (((kb >> lane) & 1ULL) && (kept + myr < POSTN))
                        keptArr[kept + myr] = ((wbase + q) << 6) + lane;
                    kept += nk;
                    if (kept >= POSTN) { kept = POSTN; done = 1; break; }
                    if (q < CW - 1) {
                        // one parallel LDS round: lane j tests column j of each later word
                        unsigned long long pr[CW];
#pragma unroll
                        for (int t = 0; t < CW; ++t)
                            pr[t] = cblk[buf][(t << 9) + (q << 6) + lane];
#pragma unroll
                        for (int t = 0; t < CW; ++t)
                            if (t > q && (pr[t] & kb)) chunk_sup |= 1u << t;
                    }
                }
            }
            if (lane == 0) { s_kept = kept; s_done = done; }
        } else {
            // ---- waves 1-7 pool: stage chunk c+1 (transposed), then B2 ----
            int t = tid - 64;                          // 0..447
            if (c + 1 < NCHUNK) {
                int wb2 = wbase + CW;
                for (int pe = t; pe < CW * 256; pe += 448) {
                    int q = pe >> 8, r = (pe & 255) << 1;
                    if (q > (r >> 6)) {                // triangle only (never read otherwise)
                        ulonglong2 v = make_ulonglong2(0ULL, 0ULL);
                        if (wb2 + q < NW && wb2 + (r >> 6) < NW)   // target+source words valid
                            v = *(const ulonglong2*)&diagw[((size_t)(wb2 + q) << 9) + r];
                        *(ulonglong2*)&cblk[nbuf][(q << 9) + r] = v;
                    }
                }
                for (int pe = t; pe < CW * 32; pe += 448) {
                    int e = pe << 1, q = e >> 6;
                    ulonglong2 v = make_ulonglong2(0ULL, 0ULL);
                    if (wb2 + q < NW) v = *(const ulonglong2*)&diagT[((size_t)wb2 << 6) + e];
                    *(ulonglong2*)&ldsT[nbuf][e] = v;
                }
            }
            {
                // B2: kept(c-1) rows into gm[words >= wbase+CW], 16B vectorized
                int w2 = wbase + CW;
                int nw2 = NW - w2;                     // always even
                int nr2 = kB - kA;
                if (c > 0 && nr2 > 0 && nw2 > 0) {
                    int npair = nw2 >> 1;
                    int tot = nr2 * npair;
                    for (int idx = t; idx < tot; idx += 448) {
                        int s = idx / npair, po = idx - s * npair;
                        int row = keptArr[kA + s];
                        ulonglong2 v = *(const ulonglong2*)&rowr[(size_t)row * NW + w2 + (po << 1)];
                        if (v.x) atomicOr(&gm[w2 + (po << 1)], v.x);
                        if (v.y) atomicOr(&gm[w2 + (po << 1) + 1], v.y);
                    }
                }
            }
        }
        __syncthreads();
        int keptNow = s_kept;
        bool fin = (s_done != 0) || (c == NCHUNK - 1);
        if (!fin && keptNow > kB) {
            // ---- B1 (all 512 threads): kept(c) rows -> next-chunk words, 16B vectorized ----
            int w1 = wbase + CW;
            int nw1 = NW - w1; if (nw1 > CW) nw1 = CW; // always even
            int npair1 = nw1 >> 1;
            int po = tid & 3;
            for (int s = kB + (tid >> 2); s < keptNow; s += 128) {
                if (po < npair1) {
                    int row = keptArr[s];
                    ulonglong2 v = *(const ulonglong2*)&rowr[(size_t)row * NW + w1 + (po << 1)];
                    if (v.x) atomicOr(&gm[w1 + (po << 1)], v.x);
                    if (v.y) atomicOr(&gm[w1 + (po << 1) + 1], v.y);
                }
            }
        }
        kA = kB;
        kB = keptNow;
        if (fin) break;
        __syncthreads();
    }
    __syncthreads();

    int kept = s_kept;
    for (int k = tid; k < POSTN; k += 512) {
        float4 bb = make_float4(0.f, 0.f, 0.f, 0.f);
        if (k < kept) bb = sortedbox[keptArr[k]];
        out[k * 5 + 0] = 0.0f;
        out[k * 5 + 1] = bb.x;
        out[k * 5 + 2] = bb.y;
        out[k * 5 + 3] = bb.z;
        out[k * 5 + 4] = bb.w;
    }
}

extern "C" void kernel_launch(void* const* d_in, const int* in_sizes, int n_in,
                              void* d_out, int out_size, void* d_ws, size_t ws_size,
                              hipStream_t stream) {
    const float* scores = (const float*)d_in[0];
    const float* deltas = (const float*)d_in[1];
    const float* iminfo = (const float*)d_in[2];
    char* w = (char*)d_ws;
    // workspace (~5.5 MB). rowr ALIASES boxes+skeys (both dead after rankscatter).
    float4*   boxes = (float4*)w;                                   // [0, 3538944)
    unsigned* skeys = (unsigned*)(w + 3538944);                     // [3538944, 4423680)
    unsigned long long* rowr = (unsigned long long*)w;              // [0, 4524032) alias
    unsigned* meta16 = (unsigned*)(w + 4786176);                    // 16 words
    unsigned long long* cbuf = (unsigned long long*)(w + 4786240);  // [4786240, 4917312)
    float4* sortedbox = (float4*)(w + 4917312);                     // [4917312, 5013568)
    unsigned long long* diagw = (unsigned long long*)(w + 5013568); // [5013568, 5398592)
    unsigned long long* diagT = (unsigned long long*)(w + 5398592); // [5398592, 5446720)
    unsigned* ghist = (unsigned*)(w + 5446720);                     // [5446720, 5479488) 32KB
    float* out = (float*)d_out;

    hipMemsetAsync(ghist, 0, NBIN13 * sizeof(unsigned), stream);    // capture-safe
    decode_kernel<<<NCELL / 256, 256, 0, stream>>>(scores, deltas, iminfo, boxes, skeys, ghist);
    compactT_kernel<<<NCB, 1024, 0, stream>>>(skeys, ghist, meta16, cbuf);
    rankscatter_kernel<<<CAP2 / 32, 256, 0, stream>>>(cbuf, meta16, boxes, sortedbox);
    matrix_kernel<<<dim3(24, 94), 256, 0, stream>>>(sortedbox, rowr, diagw, diagT);
    scan_kernel<<<1, 512, 0, stream>>>(rowr, diagw, diagT, sortedbox, out);
}